// Round 1
// baseline (299.353 us; speedup 1.0000x reference)
//
#include <hip/hip_runtime.h>
#include <hip/hip_bf16.h>
#include <stdint.h>

// ---------------------------------------------------------------------------
// EfficientDAGNN: y_k = relu(concat(prev) @ (W_k*M_k)^T + b_k), 4 layers.
// Strategy: split-bf16 MFMA (hi+lo), pure-register streaming GEMM with
// split-K, fp32 partials, phase-B reduce+bias+relu+re-split.
// Activation plane: [64][16384] bf16 (hi and lo), cols: [x | y1 | y2 | y3].
// ---------------------------------------------------------------------------

typedef __attribute__((ext_vector_type(8))) short  s8v;    // 8 bf16 (MFMA frag)
typedef __attribute__((ext_vector_type(4))) float  f4v;
typedef __attribute__((ext_vector_type(4))) unsigned short us4v;

#define LDA 16384              // activation plane leading dim (bf16 elems)
#define MFMA16x16x32 __builtin_amdgcn_mfma_f32_16x16x32_bf16

// fp32 -> bf16 RTNE (no NaNs in this problem)
__device__ __forceinline__ short f2bf(float f) {
  unsigned int u = __builtin_bit_cast(unsigned int, f);
  u += 0x7fffu + ((u >> 16) & 1u);
  return (short)(u >> 16);
}
__device__ __forceinline__ float bf2f(short s) {
  unsigned int u = ((unsigned int)(unsigned short)s) << 16;
  return __builtin_bit_cast(float, u);
}

// ---------------------------------------------------------------------------
// splitx: x (fp32 [64][4096]) -> xh/xl bf16 into cols [0,4096) of the plane
// ---------------------------------------------------------------------------
__global__ void dag_splitx(const float* __restrict__ x,
                           ushort* __restrict__ xh, ushort* __restrict__ xl) {
  int idx = blockIdx.x * blockDim.x + threadIdx.x;   // 65536 float4 units
  int m = idx >> 10;
  int n = (idx & 1023) << 2;
  f4v v = *(const f4v*)(x + (size_t)m * 4096 + n);
  us4v h, l;
#pragma unroll
  for (int j = 0; j < 4; ++j) {
    short hh = f2bf(v[j]);
    h[j] = (unsigned short)hh;
    l[j] = (unsigned short)f2bf(v[j] - bf2f(hh));
  }
  *(us4v*)(xh + (size_t)m * LDA + n) = h;
  *(us4v*)(xl + (size_t)m * LDA + n) = l;
}

// ---------------------------------------------------------------------------
// Phase A: partial[split][64][4096] = A[64][klen] @ (W*M)^T[klen][4096]
// Wave tile: 64m x 32n. No LDS, no barriers. 3-term split-bf16 MFMA.
// grid = (4096/128, SPLITK), block = 256 (4 waves side by side in n).
// ---------------------------------------------------------------------------
__global__ __launch_bounds__(256, 2) void dag_gemm_phaseA(
    const ushort* __restrict__ Ah,   // already offset to layer's col start
    const ushort* __restrict__ Al,
    const float*  __restrict__ W,    // [4096][K] row-major
    const float*  __restrict__ Mm,   // [4096][K]
    float*        __restrict__ partial,  // [SPLITK][64][4096]
    int K, int klen) {
  const int tid  = threadIdx.x;
  const int wave = tid >> 6, lane = tid & 63;
  const int l15  = lane & 15, blk = lane >> 4;
  const int n0   = blockIdx.x * 128 + wave * 32;   // wave's output-col base
  const int kbeg = blockIdx.y * klen;

  // W/M: lane reads rows (n0+l15) and (n0+16+l15), 8 consecutive k (32B)
  const float* wp0 = W  + (size_t)(n0 + l15) * K + kbeg + blk * 8;
  const float* wp1 = wp0 + (size_t)16 * K;
  const float* mp0 = Mm + (size_t)(n0 + l15) * K + kbeg + blk * 8;
  const float* mp1 = mp0 + (size_t)16 * K;
  // A: lane reads row (mt*16+l15), 8 consecutive k (16B of bf16)
  const ushort* ap  = Ah + (size_t)l15 * LDA + kbeg + blk * 8;
  const ushort* alp = Al + (size_t)l15 * LDA + kbeg + blk * 8;

  f4v acc[4][2];
#pragma unroll
  for (int i = 0; i < 4; ++i) {
    acc[i][0] = (f4v){0.f, 0.f, 0.f, 0.f};
    acc[i][1] = (f4v){0.f, 0.f, 0.f, 0.f};
  }

  struct R {
    f4v w0a, w0b, w1a, w1b, m0a, m0b, m1a, m1b;
    s8v ah0, ah1, ah2, ah3, al0, al1, al2, al3;
  } r0, r1;

  auto LOAD = [&](R& r, int ko) {
    r.w0a = *(const f4v*)(wp0 + ko);      r.w0b = *(const f4v*)(wp0 + ko + 4);
    r.w1a = *(const f4v*)(wp1 + ko);      r.w1b = *(const f4v*)(wp1 + ko + 4);
    r.m0a = *(const f4v*)(mp0 + ko);      r.m0b = *(const f4v*)(mp0 + ko + 4);
    r.m1a = *(const f4v*)(mp1 + ko);      r.m1b = *(const f4v*)(mp1 + ko + 4);
    r.ah0 = *(const s8v*)(ap  + ko);
    r.ah1 = *(const s8v*)(ap  + (size_t)16 * LDA + ko);
    r.ah2 = *(const s8v*)(ap  + (size_t)32 * LDA + ko);
    r.ah3 = *(const s8v*)(ap  + (size_t)48 * LDA + ko);
    r.al0 = *(const s8v*)(alp + ko);
    r.al1 = *(const s8v*)(alp + (size_t)16 * LDA + ko);
    r.al2 = *(const s8v*)(alp + (size_t)32 * LDA + ko);
    r.al3 = *(const s8v*)(alp + (size_t)48 * LDA + ko);
  };

  auto STEP = [&](R& r) {
    // build masked-weight hi/lo bf16 fragments (8 k-elems per nt)
    s8v wh0, wl0, wh1, wl1;
#pragma unroll
    for (int j = 0; j < 4; ++j) {
      { float w = r.w0a[j] * r.m0a[j]; short h = f2bf(w);
        wh0[j]     = h; wl0[j]     = f2bf(w - bf2f(h)); }
      { float w = r.w0b[j] * r.m0b[j]; short h = f2bf(w);
        wh0[j + 4] = h; wl0[j + 4] = f2bf(w - bf2f(h)); }
      { float w = r.w1a[j] * r.m1a[j]; short h = f2bf(w);
        wh1[j]     = h; wl1[j]     = f2bf(w - bf2f(h)); }
      { float w = r.w1b[j] * r.m1b[j]; short h = f2bf(w);
        wh1[j + 4] = h; wl1[j + 4] = f2bf(w - bf2f(h)); }
    }
    // 3-term split product: ah*wh + al*wh + ah*wl  (al*wl ~ 2^-18, dropped)
    acc[0][0] = MFMA16x16x32(r.ah0, wh0, acc[0][0], 0, 0, 0);
    acc[0][0] = MFMA16x16x32(r.al0, wh0, acc[0][0], 0, 0, 0);
    acc[0][0] = MFMA16x16x32(r.ah0, wl0, acc[0][0], 0, 0, 0);
    acc[1][0] = MFMA16x16x32(r.ah1, wh0, acc[1][0], 0, 0, 0);
    acc[1][0] = MFMA16x16x32(r.al1, wh0, acc[1][0], 0, 0, 0);
    acc[1][0] = MFMA16x16x32(r.ah1, wl0, acc[1][0], 0, 0, 0);
    acc[2][0] = MFMA16x16x32(r.ah2, wh0, acc[2][0], 0, 0, 0);
    acc[2][0] = MFMA16x16x32(r.al2, wh0, acc[2][0], 0, 0, 0);
    acc[2][0] = MFMA16x16x32(r.ah2, wl0, acc[2][0], 0, 0, 0);
    acc[3][0] = MFMA16x16x32(r.ah3, wh0, acc[3][0], 0, 0, 0);
    acc[3][0] = MFMA16x16x32(r.al3, wh0, acc[3][0], 0, 0, 0);
    acc[3][0] = MFMA16x16x32(r.ah3, wl0, acc[3][0], 0, 0, 0);
    acc[0][1] = MFMA16x16x32(r.ah0, wh1, acc[0][1], 0, 0, 0);
    acc[0][1] = MFMA16x16x32(r.al0, wh1, acc[0][1], 0, 0, 0);
    acc[0][1] = MFMA16x16x32(r.ah0, wl1, acc[0][1], 0, 0, 0);
    acc[1][1] = MFMA16x16x32(r.ah1, wh1, acc[1][1], 0, 0, 0);
    acc[1][1] = MFMA16x16x32(r.al1, wh1, acc[1][1], 0, 0, 0);
    acc[1][1] = MFMA16x16x32(r.ah1, wl1, acc[1][1], 0, 0, 0);
    acc[2][1] = MFMA16x16x32(r.ah2, wh1, acc[2][1], 0, 0, 0);
    acc[2][1] = MFMA16x16x32(r.al2, wh1, acc[2][1], 0, 0, 0);
    acc[2][1] = MFMA16x16x32(r.ah2, wl1, acc[2][1], 0, 0, 0);
    acc[3][1] = MFMA16x16x32(r.ah3, wh1, acc[3][1], 0, 0, 0);
    acc[3][1] = MFMA16x16x32(r.al3, wh1, acc[3][1], 0, 0, 0);
    acc[3][1] = MFMA16x16x32(r.ah3, wl1, acc[3][1], 0, 0, 0);
  };

  const int nsteps = klen >> 5;   // always even for our SPLITK choices
  LOAD(r0, 0);
  int ko = 0;
  for (int s = 0; s < nsteps; s += 2) {
    LOAD(r1, ko + 32);            // prefetch next step
    STEP(r0);
    if (s + 2 < nsteps) LOAD(r0, ko + 64);
    STEP(r1);
    ko += 64;
  }

  // write fp32 partials: C row m = mt*16 + blk*4 + r, col n = n0 + nt*16 + l15
  float* pout = partial + (size_t)blockIdx.y * (64 * 4096);
#pragma unroll
  for (int mt = 0; mt < 4; ++mt)
#pragma unroll
    for (int nt = 0; nt < 2; ++nt) {
      int n = n0 + nt * 16 + l15;
#pragma unroll
      for (int rr = 0; rr < 4; ++rr) {
        int m = mt * 16 + blk * 4 + rr;
        pout[(size_t)m * 4096 + n] = acc[mt][nt][rr];
      }
    }
}

// ---------------------------------------------------------------------------
// Phase B: reduce split-K partials + bias + relu; re-split to bf16 hi/lo
// (next layer's input); layer 4 writes fp32 d_out instead.
// ---------------------------------------------------------------------------
__global__ void dag_phaseB(const float* __restrict__ partial, int splitk,
                           const float* __restrict__ bias,
                           ushort* __restrict__ yh, ushort* __restrict__ yl,
                           float* __restrict__ yf) {
  int idx = blockIdx.x * blockDim.x + threadIdx.x;   // 65536 float4 units
  int m = idx >> 10;
  int n = (idx & 1023) << 2;
  const float* p = partial + (size_t)m * 4096 + n;
  f4v s = (f4v){0.f, 0.f, 0.f, 0.f};
  for (int sp = 0; sp < splitk; ++sp)
    s += *(const f4v*)(p + (size_t)sp * (64 * 4096));
  const f4v bv = *(const f4v*)(bias + n);
  f4v y;
#pragma unroll
  for (int j = 0; j < 4; ++j) y[j] = fmaxf(s[j] + bv[j], 0.f);
  if (yf) *(f4v*)(yf + (size_t)m * 4096 + n) = y;
  if (yh) {
    us4v h, l;
#pragma unroll
    for (int j = 0; j < 4; ++j) {
      short hh = f2bf(y[j]);
      h[j] = (unsigned short)hh;
      l[j] = (unsigned short)f2bf(y[j] - bf2f(hh));
    }
    *(us4v*)(yh + (size_t)m * LDA + n) = h;
    *(us4v*)(yl + (size_t)m * LDA + n) = l;
  }
}

// ---------------------------------------------------------------------------
extern "C" void kernel_launch(void* const* d_in, const int* in_sizes, int n_in,
                              void* d_out, int out_size, void* d_ws, size_t ws_size,
                              hipStream_t stream) {
  (void)in_sizes; (void)n_in; (void)out_size;
  const float* x = (const float*)d_in[0];
  struct L { const float *W, *b, *M; int K, incol, outcol; };
  L Ls[4] = {
      {(const float*)d_in[1],  (const float*)d_in[2],  (const float*)d_in[3],  4096, 0,    4096},
      {(const float*)d_in[4],  (const float*)d_in[5],  (const float*)d_in[6],  8192, 0,    8192},
      {(const float*)d_in[7],  (const float*)d_in[8],  (const float*)d_in[9],  8192, 4096, 12288},
      {(const float*)d_in[10], (const float*)d_in[11], (const float*)d_in[12], 8192, 8192, 16384},
  };
  float* out = (float*)d_out;

  // workspace: Ah(2MB) | Al(2MB) | partial(SPLITK MB)
  char* ws = (char*)d_ws;
  ushort* Ah = (ushort*)ws;
  ushort* Al = (ushort*)(ws + (size_t)64 * LDA * 2);
  float* partial = (float*)(ws + (size_t)2 * 64 * LDA * 2);
  int SPLITK = 16;
  while (SPLITK > 1 &&
         ws_size < (size_t)4 * 1024 * 1024 + (size_t)SPLITK * 1024 * 1024)
    SPLITK >>= 1;

  dag_splitx<<<256, 256, 0, stream>>>(x, Ah, Al);

  for (int k = 0; k < 4; ++k) {
    dim3 grid(32, SPLITK);
    dag_gemm_phaseA<<<grid, 256, 0, stream>>>(
        Ah + Ls[k].incol, Al + Ls[k].incol, Ls[k].W, Ls[k].M, partial,
        Ls[k].K, Ls[k].K / SPLITK);
    bool last = (k == 3);
    dag_phaseB<<<256, 256, 0, stream>>>(
        partial, SPLITK, Ls[k].b,
        last ? (ushort*)nullptr : Ah + Ls[k].outcol,
        last ? (ushort*)nullptr : Al + Ls[k].outcol,
        last ? out : (float*)nullptr);
  }
}